// Round 2
// 6921.336 us; speedup vs baseline: 1.3862x; 1.3862x over previous
//
#include <hip/hip_runtime.h>
#include <cstdint>
#include <cstddef>

// ============================================================================
// Actor rollout, round 2 (compile fix of round 1):
//  - logits GEMM via MFMA bf16 3-way-split (6 products) => f32-class
//    accuracy at ~400 TF effective (no f32 MFMA on CDNA4).
//  - softmax stats + Gumbel sampling fused into the GEMM epilogue as
//    per-strip partials; combine_k reduces; norm_probs_k normalizes dist and
//    computes probs with zero atomics.
//  - 5 kernels/step (was 6), no hipMemset, no atomicAdd.
// PRNG: JAX threefry2x32 partitionable variant (unchanged, bit-exact).
// Fix vs round 1: split3_pair returns a struct (can't bind non-const ref to
// ext_vector element in HIP/clang).
// ============================================================================

#define JAX_PARTITIONABLE 1

#define Bn 64
#define Tn 64
#define Vn 32000
#define Hn 512
#define En 256

typedef unsigned short u16;
typedef __attribute__((ext_vector_type(8))) __bf16 bf16x8;
typedef __attribute__((ext_vector_type(4))) float f32x4;
typedef __attribute__((ext_vector_type(4))) uint32_t u32x4;

// ---------------- output layout (floats) ----------------
#define OUT_SAMP 0                      // (B,T)
#define OUT_CORR (Bn * Tn)              // (B,T)
#define OUT_LOGP (2 * Bn * Tn)          // (B,T)
#define OUT_DIST (3 * Bn * Tn)          // (B,T,V) at [((b*T)+t)*V + v]
#define OUT_PROB (3 * Bn * Tn + (size_t)Bn * Tn * Vn)  // (T,V)

// ---------------- ws layout (float offsets) ----------------
#define WS_H0   0                        // B*H f32
#define WS_H1   (Bn * Hn)                // B*H f32
#define WS_G    (2 * Bn * Hn)            // B*1536 f32
#define WS_GHN  (WS_G + Bn * 3 * Hn)     // B*512 f32
#define WS_RMAX (WS_GHN + Bn * Hn)       // 64
#define WS_RLSE (WS_RMAX + Bn)           // 64
#define WS_SMP  (WS_RLSE + Bn)           // 64 (int)
#define WS_HS0  (WS_SMP + Bn)            // B*H u16 (16384 floats)
#define WS_HS1  (WS_HS0 + Bn * Hn / 2)
#define WS_HS2  (WS_HS1 + Bn * Hn / 2)
#define WS_PM   (WS_HS2 + Bn * Hn / 2)   // 500*64 f32 per-strip max
#define WS_PS   (WS_PM + Vn)             // 500*64 f32 per-strip sumexp
#define WS_PBS  (WS_PS + Vn)             // 500*64 f32 per-strip best score
#define WS_PBV  (WS_PBS + Vn)            // 500*64 int  per-strip best v
#define WS_PBZ  (WS_PBV + Vn)            // 500*64 f32  per-strip best raw z

// ---------------- threefry2x32 (Random123 / JAX schedule) ----------------
__device__ __forceinline__ void tf2x32(uint32_t k0, uint32_t k1,
                                       uint32_t x0, uint32_t x1,
                                       uint32_t& o0, uint32_t& o1) {
  uint32_t ks2 = k0 ^ k1 ^ 0x1BD11BDAu;
  x0 += k0; x1 += k1;
#define TFR(r) { x0 += x1; x1 = (x1 << r) | (x1 >> (32 - r)); x1 ^= x0; }
  TFR(13) TFR(15) TFR(26) TFR(6)  x0 += k1;  x1 += ks2 + 1u;
  TFR(17) TFR(29) TFR(16) TFR(24) x0 += ks2; x1 += k0 + 2u;
  TFR(13) TFR(15) TFR(26) TFR(6)  x0 += k0;  x1 += k1 + 3u;
  TFR(17) TFR(29) TFR(16) TFR(24) x0 += k1;  x1 += ks2 + 4u;
  TFR(13) TFR(15) TFR(26) TFR(6)  x0 += ks2; x1 += k0 + 5u;
#undef TFR
  o0 = x0; o1 = x1;
}

__device__ __forceinline__ uint32_t jax_bits32(uint32_t k0, uint32_t k1,
                                               uint32_t i, uint32_t total) {
#if JAX_PARTITIONABLE
  (void)total;
  uint32_t o0, o1; tf2x32(k0, k1, 0u, i, o0, o1); return o0 ^ o1;
#else
  uint32_t half = total >> 1;
  uint32_t o0, o1;
  if (i < half) { tf2x32(k0, k1, i, i + half, o0, o1); return o0; }
  tf2x32(k0, k1, i - half, i, o0, o1); return o1;
#endif
}

__device__ __forceinline__ void jax_splitkey(uint32_t k0, uint32_t k1,
                                             uint32_t idx, uint32_t num,
                                             uint32_t& s0, uint32_t& s1) {
#if JAX_PARTITIONABLE
  (void)num;
  tf2x32(k0, k1, 0u, idx, s0, s1);
#else
  uint32_t j0 = 2 * idx, j1 = 2 * idx + 1;
  uint32_t r0, r1;
  if (j0 < num) { tf2x32(k0, k1, j0, j0 + num, r0, r1); s0 = r0; }
  else          { tf2x32(k0, k1, j0 - num, j0, r0, r1); s0 = r1; }
  if (j1 < num) { tf2x32(k0, k1, j1, j1 + num, r0, r1); s1 = r0; }
  else          { tf2x32(k0, k1, j1 - num, j1, r0, r1); s1 = r1; }
#endif
}

__device__ __forceinline__ float bits_to_unit(uint32_t bits) {
  return __uint_as_float((bits >> 9) | 0x3F800000u) - 1.0f;
}

// ---------------- f32 -> 3x bf16 split (truncation; residual <= 2^-21) ----
struct Limbs3 { uint32_t p0, p1, p2; };

__device__ __forceinline__ Limbs3 split3_pair(float xa, float xb) {
  const uint32_t a0 = __float_as_uint(xa) & 0xFFFF0000u;
  const float ar1 = xa - __uint_as_float(a0);
  const uint32_t a1 = __float_as_uint(ar1) & 0xFFFF0000u;
  const float ar2 = ar1 - __uint_as_float(a1);
  const uint32_t a2 = __float_as_uint(ar2) & 0xFFFF0000u;
  const uint32_t b0 = __float_as_uint(xb) & 0xFFFF0000u;
  const float br1 = xb - __uint_as_float(b0);
  const uint32_t b1 = __float_as_uint(br1) & 0xFFFF0000u;
  const float br2 = br1 - __uint_as_float(b1);
  const uint32_t b2 = __float_as_uint(br2) & 0xFFFF0000u;
  Limbs3 r;
  r.p0 = (a0 >> 16) | b0;   // elem 2j in low half, 2j+1 in high half
  r.p1 = (a1 >> 16) | b1;
  r.p2 = (a2 >> 16) | b2;
  return r;
}

// ---------------- kernels ----------------

__global__ void init_k(float* h0, int* sampled) {
  int i = blockIdx.x * 256 + threadIdx.x;
  if (i < Bn * Hn) h0[i] = 0.0f;
  if (i < Bn) sampled[i] = 0;
}

// G[b,n] = x[b].w_ih[n] + h[b].w_hh[n] + b_ih[n] + b_hh[n]   (n in [0,1536), K=768)
// GHN[b,j] = h[b].w_hh[1024+j] + b_hh[1024+j]                (j in [0,512),  K=512)
__global__ void gru_gemm(const float* __restrict__ emb,
                         const float* __restrict__ w_ih, const float* __restrict__ b_ih,
                         const float* __restrict__ w_hh, const float* __restrict__ b_hh,
                         const float* __restrict__ h_prev, const int* __restrict__ sampled,
                         float* __restrict__ G, float* __restrict__ GHN) {
  const int blk = blockIdx.x;
  const bool isG = blk < 96;
  const int col0 = isG ? blk * 16 : (blk - 96) * 16;
  const int K = isG ? (En + Hn) : Hn;

  __shared__ float As[32][65];
  __shared__ float Bs[32][17];

  const int tid = threadIdx.x;
  const int tx = tid & 15;
  const int tyy = tid >> 4;
  float acc[4] = {0.f, 0.f, 0.f, 0.f};

  const int ab = tid >> 2;
  const int ak = (tid & 3) * 8;
  const int smp = sampled[ab];

  for (int k0 = 0; k0 < K; k0 += 32) {
    {
      const int kg = k0 + ak;
      const float* src;
      if (isG) src = (kg < En) ? (emb + (size_t)smp * En + kg)
                               : (h_prev + (size_t)ab * Hn + (kg - En));
      else     src = h_prev + (size_t)ab * Hn + kg;
      float4 v0 = *(const float4*)(src);
      float4 v1 = *(const float4*)(src + 4);
      As[ak + 0][ab] = v0.x; As[ak + 1][ab] = v0.y;
      As[ak + 2][ab] = v0.z; As[ak + 3][ab] = v0.w;
      As[ak + 4][ab] = v1.x; As[ak + 5][ab] = v1.y;
      As[ak + 6][ab] = v1.z; As[ak + 7][ab] = v1.w;
    }
    if (tid < 128) {
      const int c = tid >> 3;
      const int kk = (tid & 7) * 4;
      const int kg = k0 + kk;
      const int col = col0 + c;
      const float* src;
      if (isG) src = (kg < En) ? (w_ih + (size_t)col * En + kg)
                               : (w_hh + (size_t)col * Hn + (kg - En));
      else     src = w_hh + (size_t)(2 * Hn + col) * Hn + kg;
      float4 vv = *(const float4*)src;
      Bs[kk + 0][c] = vv.x; Bs[kk + 1][c] = vv.y;
      Bs[kk + 2][c] = vv.z; Bs[kk + 3][c] = vv.w;
    }
    __syncthreads();
#pragma unroll
    for (int k = 0; k < 32; k++) {
      const float w = Bs[k][tx];
#pragma unroll
      for (int i = 0; i < 4; i++) acc[i] = fmaf(As[k][tyy * 4 + i], w, acc[i]);
    }
    __syncthreads();
  }

  const int col = col0 + tx;
  if (isG) {
    const float bias = b_ih[col] + b_hh[col];
#pragma unroll
    for (int i = 0; i < 4; i++) {
      const int b = tyy * 4 + i;
      G[(size_t)b * (3 * Hn) + col] = acc[i] + bias;
    }
  } else {
    const float bias = b_hh[2 * Hn + col];
#pragma unroll
    for (int i = 0; i < 4; i++) {
      const int b = tyy * 4 + i;
      GHN[(size_t)b * Hn + col] = acc[i] + bias;
    }
  }
}

// gates + write h_new (f32) + h split into 3 bf16 limbs for the MFMA logits.
__global__ void gates_k(const float* __restrict__ G, const float* __restrict__ GHN,
                        const float* __restrict__ h_prev, float* __restrict__ h_new,
                        u16* __restrict__ hs0, u16* __restrict__ hs1,
                        u16* __restrict__ hs2) {
  const int idx = blockIdx.x * 256 + threadIdx.x;  // 0..32767
  const int b = idx >> 9, j = idx & (Hn - 1);
  const float gr = G[(size_t)b * (3 * Hn) + j];
  const float gz = G[(size_t)b * (3 * Hn) + Hn + j];
  const float gn = G[(size_t)b * (3 * Hn) + 2 * Hn + j];
  const float ghn = GHN[(size_t)b * Hn + j];
  const float r = 1.0f / (1.0f + expf(-gr));
  const float z = 1.0f / (1.0f + expf(-gz));
  const float n = tanhf((gn - ghn) + r * ghn);
  const float hp = h_prev[(size_t)b * Hn + j];
  const float h = (1.0f - z) * n + z * hp;
  h_new[idx] = h;
  const uint32_t c0 = __float_as_uint(h) & 0xFFFF0000u;
  const float r1 = h - __uint_as_float(c0);
  const uint32_t c1 = __float_as_uint(r1) & 0xFFFF0000u;
  const float r2 = r1 - __uint_as_float(c1);
  hs0[idx] = (u16)(c0 >> 16);
  hs1[idx] = (u16)(c1 >> 16);
  hs2[idx] = (u16)(__float_as_uint(r2) >> 16);
}

// Logits via MFMA split-bf16 + fused per-strip softmax/sampling partials.
// Block: 256 thr = 4 waves (2x2 of 32x32), tile 64(b) x 64(v), K=512.
// 6 MFMA products per fragment pair: a0b0,a0b1,a1b0,a1b1,a0b2,a2b0
// (dropped terms <= 2^-21 relative per product -> f32-class logits).
__global__ __launch_bounds__(256, 2) void logits_mfma(
    const u16* __restrict__ hs0, const u16* __restrict__ hs1,
    const u16* __restrict__ hs2,
    const float* __restrict__ w_out, const float* __restrict__ b_out,
    float* __restrict__ out_dist,
    float* __restrict__ pM, float* __restrict__ pS, float* __restrict__ pBS,
    int* __restrict__ pBV, float* __restrict__ pBZ, int t) {
  const int tid = threadIdx.x;
  const int w = tid >> 6;
  const int lane = tid & 63;
  const int wm = (w >> 1) * 32;      // wave row offset
  const int wn = (w & 1) * 32;       // wave col offset
  const int lr = lane & 15;          // row (A) / col (B,D)
  const int lg = lane >> 4;          // k-group (in) / row-group (out)
  const int v0 = blockIdx.x * 64;

  __shared__ int s_dr[64];
  __shared__ float ldsM[64][2], ldsS[64][2], ldsBS[64][2], ldsBZ[64][2];
  __shared__ int ldsBV[64][2];

  // PRNG keys (uniform across threads; cheap)
  uint32_t kt0, kt1, kg0, kg1;
  jax_splitkey(0u, 1u, (uint32_t)t, (uint32_t)Tn, kt0, kt1);
  jax_splitkey(kt0, kt1, 1u, 2u, kg0, kg1);
  if (tid < 64) {
    uint32_t ke0, ke1;
    jax_splitkey(kt0, kt1, 0u, 2u, ke0, ke1);
    const uint32_t eb = jax_bits32(ke0, ke1, (uint32_t)tid, (uint32_t)Bn);
    s_dr[tid] = (0.1f >= bits_to_unit(eb)) ? 1 : 0;
  }
  __syncthreads();

  f32x4 acc[2][2] = {};

#pragma unroll 2
  for (int k0 = 0; k0 < Hn; k0 += 32) {
    bf16x8 a0[2], a1[2], a2[2];
#pragma unroll
    for (int mi = 0; mi < 2; mi++) {
      const size_t off = (size_t)(wm + mi * 16 + lr) * Hn + k0 + lg * 8;
      a0[mi] = *reinterpret_cast<const bf16x8*>(hs0 + off);
      a1[mi] = *reinterpret_cast<const bf16x8*>(hs1 + off);
      a2[mi] = *reinterpret_cast<const bf16x8*>(hs2 + off);
    }
    bf16x8 bb0[2], bb1[2], bb2[2];
#pragma unroll
    for (int ni = 0; ni < 2; ni++) {
      const float* src = w_out + (size_t)(v0 + wn + ni * 16 + lr) * Hn + k0 + lg * 8;
      const float4 x0 = *(const float4*)(src);
      const float4 x1 = *(const float4*)(src + 4);
      u32x4 q0, q1, q2;
      const Limbs3 l0 = split3_pair(x0.x, x0.y);
      const Limbs3 l1 = split3_pair(x0.z, x0.w);
      const Limbs3 l2 = split3_pair(x1.x, x1.y);
      const Limbs3 l3 = split3_pair(x1.z, x1.w);
      q0[0] = l0.p0; q1[0] = l0.p1; q2[0] = l0.p2;
      q0[1] = l1.p0; q1[1] = l1.p1; q2[1] = l1.p2;
      q0[2] = l2.p0; q1[2] = l2.p1; q2[2] = l2.p2;
      q0[3] = l3.p0; q1[3] = l3.p1; q2[3] = l3.p2;
      bb0[ni] = __builtin_bit_cast(bf16x8, q0);
      bb1[ni] = __builtin_bit_cast(bf16x8, q1);
      bb2[ni] = __builtin_bit_cast(bf16x8, q2);
    }
#pragma unroll
    for (int mi = 0; mi < 2; mi++)
#pragma unroll
      for (int ni = 0; ni < 2; ni++) {
        f32x4 c = acc[mi][ni];
        c = __builtin_amdgcn_mfma_f32_16x16x32_bf16(a0[mi], bb0[ni], c, 0, 0, 0);
        c = __builtin_amdgcn_mfma_f32_16x16x32_bf16(a0[mi], bb1[ni], c, 0, 0, 0);
        c = __builtin_amdgcn_mfma_f32_16x16x32_bf16(a1[mi], bb0[ni], c, 0, 0, 0);
        c = __builtin_amdgcn_mfma_f32_16x16x32_bf16(a1[mi], bb1[ni], c, 0, 0, 0);
        c = __builtin_amdgcn_mfma_f32_16x16x32_bf16(a0[mi], bb2[ni], c, 0, 0, 0);
        c = __builtin_amdgcn_mfma_f32_16x16x32_bf16(a2[mi], bb0[ni], c, 0, 0, 0);
        acc[mi][ni] = c;
      }
  }

  // bias + store raw z (normalized in place later by norm_probs_k)
  float bias[2];
#pragma unroll
  for (int ni = 0; ni < 2; ni++) bias[ni] = b_out[v0 + wn + ni * 16 + lr];
#pragma unroll
  for (int mi = 0; mi < 2; mi++)
#pragma unroll
    for (int ni = 0; ni < 2; ni++)
#pragma unroll
      for (int r = 0; r < 4; r++) {
        acc[mi][ni][r] += bias[ni];
        const int brow = wm + mi * 16 + lg * 4 + r;
        out_dist[(size_t)(brow * Tn + t) * Vn + v0 + wn + ni * 16 + lr] =
            acc[mi][ni][r];
      }

  // per-(row, 64-col-strip) partials: strip max, strip sumexp, Gumbel best.
  // Scoring on RAW z: argmax is invariant to the per-row (m+l) shift.
  const float LU = -logf((float)Vn);
#pragma unroll
  for (int mi = 0; mi < 2; mi++) {
#pragma unroll
    for (int r = 0; r < 4; r++) {
      const int brow = wm + mi * 16 + lg * 4 + r;
      const int dr = s_dr[brow];
      const int vA = v0 + wn + lr, vB = vA + 16;
      const float zA = acc[mi][0][r], zB = acc[mi][1][r];
      float mz = fmaxf(zA, zB);
#pragma unroll
      for (int off = 1; off < 16; off <<= 1) mz = fmaxf(mz, __shfl_xor(mz, off, 64));
      float sz = expf(zA - mz) + expf(zB - mz);
#pragma unroll
      for (int off = 1; off < 16; off <<= 1) sz += __shfl_xor(sz, off, 64);
      const uint32_t bA = jax_bits32(kg0, kg1, (uint32_t)(brow * Vn + vA), 0u);
      const uint32_t bB = jax_bits32(kg0, kg1, (uint32_t)(brow * Vn + vB), 0u);
      const float uA = fmaxf(1e-9f, bits_to_unit(bA) + 1e-9f);
      const float uB = fmaxf(1e-9f, bits_to_unit(bB) + 1e-9f);
      const float glA = logf(-logf(uA));
      const float glB = logf(-logf(uB));
      const float sA = (dr ? LU : zA) - glA;
      const float sB = (dr ? LU : zB) - glB;
      float bs; int bv; float bz;
      if (sB > sA) { bs = sB; bv = vB; bz = zB; }
      else         { bs = sA; bv = vA; bz = zA; }
#pragma unroll
      for (int off = 1; off < 16; off <<= 1) {
        const float so = __shfl_xor(bs, off, 64);
        const int vo = __shfl_xor(bv, off, 64);
        const float zo = __shfl_xor(bz, off, 64);
        if (so > bs || (so == bs && vo < bv)) { bs = so; bv = vo; bz = zo; }
      }
      if (lr == 0) {
        ldsM[brow][w & 1] = mz; ldsS[brow][w & 1] = sz;
        ldsBS[brow][w & 1] = bs; ldsBV[brow][w & 1] = bv; ldsBZ[brow][w & 1] = bz;
      }
    }
  }
  __syncthreads();
  if (tid < 64) {
    const float m0 = ldsM[tid][0], m1 = ldsM[tid][1];
    const float mm = fmaxf(m0, m1);
    const float ss = ldsS[tid][0] * expf(m0 - mm) + ldsS[tid][1] * expf(m1 - mm);
    float bs = ldsBS[tid][0]; int bv = ldsBV[tid][0]; float bz = ldsBZ[tid][0];
    if (ldsBS[tid][1] > bs || (ldsBS[tid][1] == bs && ldsBV[tid][1] < bv)) {
      bs = ldsBS[tid][1]; bv = ldsBV[tid][1]; bz = ldsBZ[tid][1];
    }
    const int o = blockIdx.x * 64 + tid;   // [strip][row], coalesced
    pM[o] = mm; pS[o] = ss; pBS[o] = bs; pBV[o] = bv; pBZ[o] = bz;
  }
}

// Reduce 500 strips per row -> m, lse, sample, logprob, correction.
__global__ __launch_bounds__(256) void combine_k(
    const float* __restrict__ pM, const float* __restrict__ pS,
    const float* __restrict__ pBS, const int* __restrict__ pBV,
    const float* __restrict__ pBZ,
    float* __restrict__ rmax, float* __restrict__ rlse,
    int* __restrict__ sampled, float* __restrict__ out, int t) {
  const int row = blockIdx.x, tid = threadIdx.x;
  const int NB = Vn / 64;  // 500 strips
  float mj[2] = {-INFINITY, -INFINITY}, sj[2] = {0.f, 0.f};
  float lbs = -INFINITY; int lbv = Vn; float lbz = 0.f;
#pragma unroll
  for (int q = 0; q < 2; q++) {
    const int j = tid + q * 256;
    if (j < NB) {
      const int o = j * 64 + row;
      mj[q] = pM[o]; sj[q] = pS[o];
      const float b = pBS[o]; const int v = pBV[o];
      if (b > lbs || (b == lbs && v < lbv)) { lbs = b; lbv = v; lbz = pBZ[o]; }
    }
  }
  __shared__ float rm[256], rs[256], rb[256], rz[256];
  __shared__ int rv[256];
  rm[tid] = fmaxf(mj[0], mj[1]); __syncthreads();
  for (int s = 128; s > 0; s >>= 1) {
    if (tid < s) rm[tid] = fmaxf(rm[tid], rm[tid + s]);
    __syncthreads();
  }
  const float mm = rm[0];
  float ls = 0.f;
#pragma unroll
  for (int q = 0; q < 2; q++)
    if (tid + q * 256 < NB) ls += sj[q] * expf(mj[q] - mm);
  rs[tid] = ls; rb[tid] = lbs; rv[tid] = lbv; rz[tid] = lbz; __syncthreads();
  for (int s = 128; s > 0; s >>= 1) {
    if (tid < s) {
      rs[tid] += rs[tid + s];
      if (rb[tid + s] > rb[tid] || (rb[tid + s] == rb[tid] && rv[tid + s] < rv[tid])) {
        rb[tid] = rb[tid + s]; rv[tid] = rv[tid + s]; rz[tid] = rz[tid + s];
      }
    }
    __syncthreads();
  }
  if (tid == 0) {
    const float l = logf(rs[0]);
    rmax[row] = mm; rlse[row] = l;
    const int v = rv[0];
    const float d = (rz[0] - mm) - l;   // same op order as norm_probs_k
    sampled[row] = v;
    out[OUT_SAMP + row * Tn + t] = (float)v;
    out[OUT_LOGP + row * Tn + t] = d;
    uint32_t kt0, kt1, ke0, ke1;
    jax_splitkey(0u, 1u, (uint32_t)t, (uint32_t)Tn, kt0, kt1);
    jax_splitkey(kt0, kt1, 0u, 2u, ke0, ke1);
    const int dr =
        (0.1f >= bits_to_unit(jax_bits32(ke0, ke1, (uint32_t)row, (uint32_t)Bn)))
            ? 1 : 0;
    const float LU = -logf((float)Vn);
    const float onp = fminf(fmaxf(expf(d), 1e-8f), 1.0f);
    const float offp = fminf(fmaxf(expf(dr ? LU : d), 1e-8f), 1.0f);
    out[OUT_CORR + row * Tn + t] = onp / offp;
  }
}

// Normalize z -> dist in place; probs[t,v] = mean_b exp(dist). No atomics.
__global__ void norm_probs_k(float* __restrict__ out_dist,
                             float* __restrict__ probs,
                             const float* __restrict__ rmax,
                             const float* __restrict__ rlse, int t) {
  __shared__ float sm[64], sl[64];
  const int tid = threadIdx.x;
  if (tid < 64) { sm[tid] = rmax[tid]; sl[tid] = rlse[tid]; }
  __syncthreads();
  const int v = blockIdx.x * 64 + (tid & 63);
  const int bq = tid >> 6;       // 0..3, each sums 16 rows
  float s = 0.f;
#pragma unroll
  for (int i = 0; i < 16; i++) {
    const int b = bq * 16 + i;
    float* p = out_dist + (size_t)(b * Tn + t) * Vn + v;
    const float d = (*p - sm[b]) - sl[b];
    *p = d;
    s += expf(d);
  }
  __shared__ float red[256];
  red[tid] = s; __syncthreads();
  if (bq == 0)
    probs[(size_t)t * Vn + v] =
        (red[tid] + red[tid + 64] + red[tid + 128] + red[tid + 192]) * 0.015625f;
}

// ---------------- host ----------------
extern "C" void kernel_launch(void* const* d_in, const int* in_sizes, int n_in,
                              void* d_out, int out_size, void* d_ws, size_t ws_size,
                              hipStream_t stream) {
  const float* emb   = (const float*)d_in[0];
  const float* w_ih  = (const float*)d_in[1];
  const float* b_ih  = (const float*)d_in[2];
  const float* w_hh  = (const float*)d_in[3];
  const float* b_hh  = (const float*)d_in[4];
  const float* w_out = (const float*)d_in[5];
  const float* b_out = (const float*)d_in[6];
  float* out = (float*)d_out;
  float* ws  = (float*)d_ws;

  float* h_buf[2] = { ws + WS_H0, ws + WS_H1 };
  float* G    = ws + WS_G;
  float* GHN  = ws + WS_GHN;
  float* rmax = ws + WS_RMAX;
  float* rlse = ws + WS_RLSE;
  int*   smp  = (int*)(ws + WS_SMP);
  u16*   hs0  = (u16*)(ws + WS_HS0);
  u16*   hs1  = (u16*)(ws + WS_HS1);
  u16*   hs2  = (u16*)(ws + WS_HS2);
  float* pM   = ws + WS_PM;
  float* pS   = ws + WS_PS;
  float* pBS  = ws + WS_PBS;
  int*   pBV  = (int*)(ws + WS_PBV);
  float* pBZ  = ws + WS_PBZ;

  init_k<<<(Bn * Hn + 255) / 256, 256, 0, stream>>>(h_buf[0], smp);

  for (int t = 0; t < Tn; t++) {
    float* hp = h_buf[t & 1];
    float* hn = h_buf[(t + 1) & 1];
    gru_gemm<<<128, 256, 0, stream>>>(emb, w_ih, b_ih, w_hh, b_hh, hp, smp, G, GHN);
    gates_k<<<(Bn * Hn) / 256, 256, 0, stream>>>(G, GHN, hp, hn, hs0, hs1, hs2);
    logits_mfma<<<Vn / 64, 256, 0, stream>>>(hs0, hs1, hs2, w_out, b_out,
                                             out + OUT_DIST, pM, pS, pBS, pBV, pBZ, t);
    combine_k<<<Bn, 256, 0, stream>>>(pM, pS, pBS, pBV, pBZ, rmax, rlse, smp, out, t);
    norm_probs_k<<<Vn / 64, 256, 0, stream>>>(out + OUT_DIST, out + OUT_PROB,
                                              rmax, rlse, t);
  }
}